// Round 1
// baseline (732.099 us; speedup 1.0000x reference)
//
#include <hip/hip_runtime.h>

// RoutingCapsule: B=32, N_in=2048, N_out=64, D_out=32, D_in=16
// R4: same 5-sweep math as R3 (bit-identical numerics), plus:
//   - squash fused into passA/s_kernel via last-block-per-j rendezvous
//     (11 -> 8 dispatches; squash parallelism unchanged at 64 blocks)
//   - nontemporal W loads in passA: keep the 128MB Wb L3-resident for the
//     4 subsequent sweeps instead of letting the 256MB one-shot W stream
//     thrash the 256MB Infinity Cache
//   - explicit zero-accumulator hoist in t/s MFMA loops

#define B_   32
#define NI   2048
#define NO   64
#define DO_  32
#define DI   16
#define IC   16
#define WSTRIDE ((size_t)NO * DO_ * DI)

typedef __bf16 bf16x8 __attribute__((ext_vector_type(8)));
typedef float  f32x16 __attribute__((ext_vector_type(16)));
typedef float  f32x4v __attribute__((ext_vector_type(4)));
union U16B { uint4 u; bf16x8 v; };

// ---------------- last-block rendezvous (split-K pattern) ----------------
// Returns true for exactly the last-arriving block of the 'arrivals'-sized
// group sharing cnt[idx]. Counter must be zeroed earlier in the same call.
__device__ __forceinline__ bool last_block(int* cnt, int idx, int tid, int arrivals)
{
    __shared__ int lastf;
    __syncthreads();                 // all block stores issued; vmcnt drained at barrier
    if (tid == 0) {
        __threadfence();             // release: part[] writes visible device-wide
        const int prev = atomicAdd(cnt + idx, 1);   // device scope by default
        lastf = (prev == arrivals - 1) ? 1 : 0;
        if (lastf) __threadfence();  // acquire: invalidate stale L1/L2 lines
    }
    __syncthreads();
    return lastf != 0;
}

// ---------------- squash tail (identical math to old squash_kernel) ------
__device__ __forceinline__ void squash_tail(const float* __restrict__ part,
                                            const float* __restrict__ bias,
                                            const float* __restrict__ v0T,
                                            float* __restrict__ outp,
                                            int j, int tid, int mode, float prescale)
{
    __shared__ float red[8][32];
    __shared__ float scl[32];
    const int b = tid & 31;
    const int g = tid >> 5;
    const int d0 = g * 4;

    float sv[4];
    #pragma unroll
    for (int q = 0; q < 4; ++q) {
        const float* p = part + (size_t)j * 1024 + (d0 + q) * 32 + b;
        float a = 0.f;
        #pragma unroll
        for (int ch = 0; ch < 32; ++ch) a += p[(size_t)ch * NO * 1024];
        sv[q] = a * prescale + bias[j * DO_ + d0 + q];
    }

    float p2s = 0.f;
    #pragma unroll
    for (int q = 0; q < 4; ++q) p2s = fmaf(sv[q], sv[q], p2s);
    red[g][b] = p2s;
    __syncthreads();
    if (tid < 32) {
        float n2 = 0.f;
        #pragma unroll
        for (int gg = 0; gg < 8; ++gg) n2 += red[gg][tid];
        scl[tid] = n2 / ((1.0f + n2) * sqrtf(n2 + 1e-7f));
    }
    __syncthreads();
    const float sc = scl[b];
    #pragma unroll
    for (int q = 0; q < 4; ++q) {
        const int d = d0 + q;
        const float vq = sv[q] * sc;
        if (mode == 0)      outp[((size_t)j * DO_ + d) * B_ + b] = vq;
        else if (mode == 1) outp[((size_t)j * DO_ + d) * B_ + b] =
                                v0T[((size_t)j * DO_ + d) * B_ + b] + vq;
        else                outp[((size_t)b * NO + j) * DO_ + d] = vq;
    }
}

// ---------------- x -> xT bf16 in exact B-fragment order ----------------
// xT[((i*2+h)*32+m)*8 + e] = x[m][i][8h+e];  also zeroes rendezvous counters.
__global__ __launch_bounds__(256) void convert_xT_kernel(const float* __restrict__ x,
                                                         __bf16* __restrict__ xT,
                                                         int* __restrict__ cnt)
{
    const int idx = blockIdx.x * 256 + threadIdx.x;   // 131072 = 2048*2*32
    if (idx < 192) cnt[idx] = 0;                      // 3 sets of 64 counters
    const int m = idx & 31;
    const int h = (idx >> 5) & 1;
    const int i = idx >> 6;
    const float4 f0 = *(const float4*)(x + ((size_t)m * NI + i) * DI + 8 * h);
    const float4 f1 = *(const float4*)(x + ((size_t)m * NI + i) * DI + 8 * h + 4);
    __bf16 o[8] = {(__bf16)f0.x, (__bf16)f0.y, (__bf16)f0.z, (__bf16)f0.w,
                   (__bf16)f1.x, (__bf16)f1.y, (__bf16)f1.z, (__bf16)f1.w};
    *(uint4*)(xT + (size_t)idx * 8) = *(uint4*)o;
}

// ---------------- pass A: convert W + s0 partials (+fused squash0) -------
__global__ __launch_bounds__(256) void passA_kernel(const float* __restrict__ W,
                                                    const __bf16* __restrict__ xT,
                                                    __bf16* __restrict__ Wb,
                                                    float* __restrict__ part,
                                                    const float* __restrict__ bias,
                                                    float* __restrict__ v0T,
                                                    int* __restrict__ cnt)
{
    __shared__ float lds[4][1024];
    const int tid = threadIdx.x, lane = tid & 63, w = tid >> 6;
    const int j  = blockIdx.x & 63;
    const int ch = blockIdx.x >> 6;
    const int i0 = ch * 64 + w * IC;
    const int m  = lane & 31, h = lane >> 5;

    const size_t toff = (((size_t)i0 * NO + j) * DO_ + m) * DI + 8 * h;
    const float*  Wp  = W  + toff;
    __bf16*       Wbp = Wb + toff;
    const __bf16* xp  = xT + (size_t)i0 * 512 + lane * 8;

    f32x16 acc;
    #pragma unroll
    for (int r = 0; r < 16; ++r) acc[r] = 0.0f;

    #pragma unroll 4
    for (int ii = 0; ii < IC; ++ii) {
        // nontemporal: W is read exactly once per call; keep it from
        // evicting the freshly-written Wb out of the Infinity Cache.
        const f32x4v w0 = __builtin_nontemporal_load((const f32x4v*)Wp);
        const f32x4v w1 = __builtin_nontemporal_load((const f32x4v*)Wp + 1);
        U16B a;
        a.v[0] = (__bf16)w0[0]; a.v[1] = (__bf16)w0[1]; a.v[2] = (__bf16)w0[2]; a.v[3] = (__bf16)w0[3];
        a.v[4] = (__bf16)w1[0]; a.v[5] = (__bf16)w1[1]; a.v[6] = (__bf16)w1[2]; a.v[7] = (__bf16)w1[3];
        *(uint4*)Wbp = a.u;
        U16B b; b.u = *(const uint4*)xp;
        acc = __builtin_amdgcn_mfma_f32_32x32x16_bf16(a.v, b.v, acc, 0, 0, 0);
        Wp += WSTRIDE; Wbp += WSTRIDE; xp += 512;
    }

    #pragma unroll
    for (int r = 0; r < 16; ++r) {
        const int row = (r & 3) + 8 * (r >> 2) + 4 * h;
        lds[w][row * 32 + m] = acc[r];
    }
    __syncthreads();
    float* pb = part + ((size_t)ch * NO + j) * 1024;
    #pragma unroll
    for (int q = 0; q < 4; ++q) {
        const int idx = tid + 256 * q;
        pb[idx] = lds[0][idx] + lds[1][idx] + lds[2][idx] + lds[3][idx];
    }

    if (last_block(cnt, j, tid, 32))
        squash_tail(part, bias, nullptr, v0T, j, tid, 0, 1.0f / 64.0f);
}

// ---------------- s-pass (+fused squash) ----------------
__global__ __launch_bounds__(256) void s_kernel(const __bf16* __restrict__ Wb,
                                                const __bf16* __restrict__ xT,
                                                const float* __restrict__ c,
                                                float* __restrict__ part,
                                                const float* __restrict__ bias,
                                                const float* __restrict__ v0T,
                                                float* __restrict__ outp,
                                                int* __restrict__ cnt,
                                                int mode, float prescale)
{
    __shared__ float lds[4][1024];
    const int tid = threadIdx.x, lane = tid & 63, w = tid >> 6;
    const int j  = blockIdx.x & 63;
    const int ch = blockIdx.x >> 6;
    const int i0 = ch * 64 + w * IC;
    const int m  = lane & 31, h = lane >> 5;

    const __bf16* Wp = Wb + (((size_t)i0 * NO + j) * DO_ + m) * DI + 8 * h;
    const __bf16* xp = xT + (size_t)i0 * 512 + lane * 8;
    const float*  cp = c  + (size_t)i0 * (NO * B_) + j * B_ + m;

    f32x16 acc, z;
    #pragma unroll
    for (int r = 0; r < 16; ++r) { acc[r] = 0.0f; z[r] = 0.0f; }

    #pragma unroll 4
    for (int ii = 0; ii < IC; ++ii) {
        U16B a; a.u = *(const uint4*)Wp;
        U16B b; b.u = *(const uint4*)xp;
        const float cv = *cp;
        f32x16 u = __builtin_amdgcn_mfma_f32_32x32x16_bf16(a.v, b.v, z, 0, 0, 0);
        #pragma unroll
        for (int r = 0; r < 16; ++r) acc[r] = fmaf(cv, u[r], acc[r]);
        Wp += WSTRIDE; xp += 512; cp += NO * B_;
    }

    #pragma unroll
    for (int r = 0; r < 16; ++r) {
        const int row = (r & 3) + 8 * (r >> 2) + 4 * h;
        lds[w][row * 32 + m] = acc[r];
    }
    __syncthreads();
    float* pb = part + ((size_t)ch * NO + j) * 1024;
    #pragma unroll
    for (int q = 0; q < 4; ++q) {
        const int idx = tid + 256 * q;
        pb[idx] = lds[0][idx] + lds[1][idx] + lds[2][idx] + lds[3][idx];
    }

    if (last_block(cnt, j, tid, 32))
        squash_tail(part, bias, v0T, outp, j, tid, mode, prescale);
}

// ---------------- t-pass ----------------
__global__ __launch_bounds__(256) void t_kernel(const __bf16* __restrict__ Wb,
                                                const __bf16* __restrict__ xT,
                                                const float* __restrict__ vT,
                                                float* __restrict__ t)
{
    const int tid = threadIdx.x, lane = tid & 63;
    const int wid = blockIdx.x * 4 + (tid >> 6);
    const int j   = wid & 63;
    const int i0  = (wid >> 6) * IC;
    const int m   = lane & 31, h = lane >> 5;

    const __bf16* Wp = Wb + (((size_t)i0 * NO + j) * DO_ + m) * DI + 8 * h;
    const __bf16* xp = xT + (size_t)i0 * 512 + lane * 8;

    float vr[16];
    #pragma unroll
    for (int r = 0; r < 16; ++r) {
        const int row = (r & 3) + 8 * (r >> 2) + 4 * h;
        vr[r] = vT[((size_t)j * DO_ + row) * B_ + m];
    }

    f32x16 z;
    #pragma unroll
    for (int r = 0; r < 16; ++r) z[r] = 0.0f;

    #pragma unroll 4
    for (int ii = 0; ii < IC; ++ii) {
        U16B a; a.u = *(const uint4*)Wp;
        U16B b; b.u = *(const uint4*)xp;
        f32x16 u = __builtin_amdgcn_mfma_f32_32x32x16_bf16(a.v, b.v, z, 0, 0, 0);

        float p0 = 0.f, p1 = 0.f, p2 = 0.f, p3 = 0.f;
        #pragma unroll
        for (int r = 0; r < 16; r += 4) {
            p0 = fmaf(u[r + 0], vr[r + 0], p0);
            p1 = fmaf(u[r + 1], vr[r + 1], p1);
            p2 = fmaf(u[r + 2], vr[r + 2], p2);
            p3 = fmaf(u[r + 3], vr[r + 3], p3);
        }
        float tp = (p0 + p1) + (p2 + p3);
        tp += __shfl_xor(tp, 32);
        if (h == 0) t[(size_t)(i0 + ii) * (NO * B_) + j * B_ + m] = tp;
        Wp += WSTRIDE; xp += 512;
    }
}

// ---------------- softmax over j per (i,b), in place ----------------
__global__ __launch_bounds__(256) void softmax_kernel(float* __restrict__ t)
{
    __shared__ float red[8][32];
    __shared__ float row_m[32];
    __shared__ float row_s[32];
    const int i = blockIdx.x;
    const int tid = threadIdx.x;
    const int b = tid & 31;
    const int g = tid >> 5;
    float* base = t + (size_t)i * (NO * B_);

    float tv[8];
    #pragma unroll
    for (int k = 0; k < 8; ++k) tv[k] = base[(g * 8 + k) * B_ + b];

    float m8 = tv[0];
    #pragma unroll
    for (int k = 1; k < 8; ++k) m8 = fmaxf(m8, tv[k]);
    red[g][b] = m8;
    __syncthreads();
    if (tid < 32) {
        float mm = red[0][tid];
        #pragma unroll
        for (int gg = 1; gg < 8; ++gg) mm = fmaxf(mm, red[gg][tid]);
        row_m[tid] = mm;
    }
    __syncthreads();
    const float mm = row_m[b];
    float e[8]; float ps = 0.f;
    #pragma unroll
    for (int k = 0; k < 8; ++k) { e[k] = __expf(tv[k] - mm); ps += e[k]; }
    __syncthreads();
    red[g][b] = ps;
    __syncthreads();
    if (tid < 32) {
        float ss = 0.f;
        #pragma unroll
        for (int gg = 0; gg < 8; ++gg) ss += red[gg][tid];
        row_s[tid] = 1.0f / ss;
    }
    __syncthreads();
    const float inv = row_s[b];
    #pragma unroll
    for (int k = 0; k < 8; ++k) base[(g * 8 + k) * B_ + b] = e[k] * inv;
}

extern "C" void kernel_launch(void* const* d_in, const int* in_sizes, int n_in,
                              void* d_out, int out_size, void* d_ws, size_t ws_size,
                              hipStream_t stream)
{
    const float* x    = (const float*)d_in[0];
    const float* W    = (const float*)d_in[1];
    const float* bias = (const float*)d_in[2];
    float* out = (float*)d_out;

    char* ws = (char*)d_ws;
    __bf16* Wb   = (__bf16*)ws;                                   // 128 MB
    __bf16* xT   = (__bf16*)(ws + (size_t)134217728);             // 2 MB
    float*  t_buf= (float*) (ws + (size_t)134217728 + 2097152);   // 16 MB
    float*  part = (float*) (ws + (size_t)134217728 + 2097152 + 16777216); // 8 MB
    float*  v0T  = (float*) (ws + (size_t)134217728 + 2097152 + 16777216 + 8388608);
    float*  vsT  = v0T + (size_t)NO * DO_ * B_;
    int*    cnt  = (int*)  (ws + (size_t)162004992);              // 192 ints, after vsT

    const dim3 tW(256);
    const dim3 gX(512), gP(2048), gSm(NI);

    convert_xT_kernel<<<gX, tW, 0, stream>>>(x, xT, cnt);

    // sweep 1: convert W -> Wb, s0 partials, fused squash0 -> v0T
    passA_kernel<<<gP, tW, 0, stream>>>(W, xT, Wb, part, bias, v0T, cnt);

    // iteration 1
    t_kernel<<<gP, tW, 0, stream>>>(Wb, xT, v0T, t_buf);
    softmax_kernel<<<gSm, tW, 0, stream>>>(t_buf);
    s_kernel<<<gP, tW, 0, stream>>>(Wb, xT, t_buf, part, bias, v0T, vsT,
                                    cnt + 64, 1, 1.0f);   // vsT = v0 + v1

    // iteration 2
    t_kernel<<<gP, tW, 0, stream>>>(Wb, xT, vsT, t_buf);
    softmax_kernel<<<gSm, tW, 0, stream>>>(t_buf);
    s_kernel<<<gP, tW, 0, stream>>>(Wb, xT, t_buf, part, bias, nullptr, out,
                                    cnt + 128, 2, 1.0f);  // final v -> out
}